// Round 1
// baseline (552.604 us; speedup 1.0000x reference)
//
#include <hip/hip_runtime.h>

// Problem constants
#define S_LEN 512
#define BATCH 16
#define DMODEL 512
#define NHEAD 8
#define DH 64
#define NI 16      // loop count = x.shape[1] = 16 channel iterations

typedef float f32x4 __attribute__((ext_vector_type(4)));
typedef short s16x8 __attribute__((ext_vector_type(8)));

__device__ __forceinline__ unsigned short f2bf(float f){
  unsigned int u = __float_as_uint(f);
  u += 0x7FFFu + ((u >> 16) & 1u);   // RNE
  return (unsigned short)(u >> 16);
}

// ---------------- convert f32 -> bf16 (4 elems/thread) ----------------
__global__ void k_cvt(const float* __restrict__ src, unsigned short* __restrict__ dst){
  int t = blockIdx.x * 256 + threadIdx.x;
  float4 v = reinterpret_cast<const float4*>(src)[t];
  ushort4 o;
  o.x = f2bf(v.x); o.y = f2bf(v.y); o.z = f2bf(v.z); o.w = f2bf(v.w);
  reinterpret_cast<ushort4*>(dst)[t] = o;
}

// ---------------- zcol[b][i][t] = x[t][b][i] ----------------
__global__ void k_zcol(const float* __restrict__ x, float* __restrict__ zcol){
  int tid = blockIdx.x * 256 + threadIdx.x;     // 16*16*512 = 131072
  int t = tid & 511; int bi = tid >> 9; int b = bi >> 4; int i = bi & 15;
  zcol[tid] = x[(size_t)(t * BATCH + b) * DMODEL + i];
}

// ---------------- Kf (f32) and Vf (bf16) projections: C = X @ W^T + b ----------------
// rows r = s*B+b (8192), cols c in [0,1024): c<512 -> K, else V. W row = 512+c for both.
__global__ __launch_bounds__(256) void k_kvgemm(const unsigned short* __restrict__ xb,
    const unsigned short* __restrict__ Winb, const float* __restrict__ b_in,
    float* __restrict__ Kf, unsigned short* __restrict__ Vfb){
  int w = threadIdx.x >> 6, l = threadIdx.x & 63;
  int kb = l >> 4, ln = l & 15;
  int m0 = blockIdx.x * 64 + w * 16;
  int c  = blockIdx.y * 16 + ln;
  const unsigned short* ap = xb + (size_t)(m0 + ln) * DMODEL + kb * 8;
  const unsigned short* bp = Winb + (size_t)(512 + c) * DMODEL + kb * 8;
  f32x4 acc = {0.f, 0.f, 0.f, 0.f};
  #pragma unroll
  for (int k0 = 0; k0 < DMODEL; k0 += 32){
    s16x8 a = *reinterpret_cast<const s16x8*>(ap + k0);
    s16x8 b = *reinterpret_cast<const s16x8*>(bp + k0);
    acc = __builtin_amdgcn_mfma_f32_16x16x32_bf16(a, b, acc, 0, 0, 0);
  }
  float bias = b_in[512 + c];
  #pragma unroll
  for (int r = 0; r < 4; ++r){
    int m = m0 + kb * 4 + r;
    float v = acc[r] + bias;
    if (c < DMODEL) Kf[(size_t)m * DMODEL + c] = v;
    else            Vfb[(size_t)m * DMODEL + (c - DMODEL)] = f2bf(v);
  }
}

// ---------------- transpose Vfb [t*B+b][d] -> VfT [b][d][t] (bf16) ----------------
__global__ void k_tr(const unsigned short* __restrict__ Vfb, unsigned short* __restrict__ VfT){
  __shared__ unsigned short tile[32][34];
  int b = blockIdx.z; int t0 = blockIdx.x * 32; int d0 = blockIdx.y * 32;
  int tx = threadIdx.x & 31, ty = threadIdx.x >> 5;   // 32 x 8
  #pragma unroll
  for (int k = 0; k < 4; ++k){
    int row = ty + 8 * k;
    tile[row][tx] = Vfb[(size_t)((t0 + row) * BATCH + b) * DMODEL + d0 + tx];
  }
  __syncthreads();
  #pragma unroll
  for (int k = 0; k < 4; ++k){
    int row = ty + 8 * k;
    VfT[(size_t)b * (DMODEL * S_LEN) + (size_t)(d0 + row) * S_LEN + t0 + tx] = tile[tx][row];
  }
}

// ---------------- G,H precompute: per (b,h): G[bh][i][t], H[bh][i][t] ----------------
// A_ti = Wq[h*64+:,i] . Kf[t,b,hslice];  Bt = bq[hslice] . Kf;  alpha,beta per i
__global__ __launch_bounds__(512) void k_gh(const float* __restrict__ W_in,
    const float* __restrict__ b_in, const float* __restrict__ Kf,
    const float* __restrict__ zcol, float* __restrict__ G, float* __restrict__ H){
  int bh = blockIdx.x; int b = bh >> 3, h = bh & 7;
  __shared__ float u[64][17];     // u[d][i] = Wq[h*64+d][i]
  __shared__ float cvec[64];      // bq[hslice]
  __shared__ float alpha[16], beta[16];
  int tid = threadIdx.x;
  for (int idx = tid; idx < 1024; idx += 512){
    int d = idx >> 4, i = idx & 15;
    u[d][i] = W_in[(size_t)(h * 64 + d) * DMODEL + i];
  }
  if (tid < 64) cvec[tid] = b_in[h * 64 + tid];
  __syncthreads();
  if (tid < 16){
    float a = 0.f, be = 0.f;
    for (int d = 0; d < 64; ++d){
      float wk = W_in[(size_t)(512 + h * 64 + d) * DMODEL + tid];
      a  += u[d][tid] * wk;
      be += cvec[d] * wk;
    }
    alpha[tid] = a; beta[tid] = be;
  }
  __syncthreads();
  int t = tid;  // 0..511
  float K[64];
  const float* kp = Kf + (size_t)(t * BATCH + b) * DMODEL + h * 64;
  #pragma unroll
  for (int d = 0; d < 64; d += 4){
    float4 v = *reinterpret_cast<const float4*>(kp + d);
    K[d] = v.x; K[d+1] = v.y; K[d+2] = v.z; K[d+3] = v.w;
  }
  float Bt = 0.f;
  #pragma unroll
  for (int d = 0; d < 64; ++d) Bt += cvec[d] * K[d];
  for (int i = 0; i < 16; ++i){
    float A = 0.f;
    #pragma unroll
    for (int d = 0; d < 64; ++d) A += u[d][i] * K[d];
    float z = zcol[(size_t)(b * 16 + i) * 512 + t];
    G[(size_t)(bh * 16 + i) * 512 + t] = (A  - alpha[i] * z) * 0.125f;
    H[(size_t)(bh * 16 + i) * 512 + t] = (Bt - beta[i]  * z) * 0.125f;
  }
}

// ---------------- softmax accumulate: Pbar rows + r_i ----------------
// grid: 32(bh in chunk) * 8(sb) blocks, 512 thr (8 waves); wave handles 8 s rows.
__global__ __launch_bounds__(512) void k_sm(const float* __restrict__ G,
    const float* __restrict__ H, const float* __restrict__ zcol, int bh0,
    float* __restrict__ R, unsigned short* __restrict__ Pb){
  int blk = blockIdx.x; int bhl = blk >> 3; int sb = blk & 7;
  int bh = bh0 + bhl; int b = bh >> 3;
  __shared__ float Gl[512], Hl[512], Zl[512];
  int tid = threadIdx.x, lane = tid & 63, w = tid >> 6;
  float Pacc[8][8];
  #pragma unroll
  for (int a = 0; a < 8; ++a)
    #pragma unroll
    for (int j = 0; j < 8; ++j) Pacc[a][j] = 0.f;

  for (int i = 0; i < NI; ++i){
    Gl[tid] = G[(size_t)(bh * 16 + i) * 512 + tid];
    Hl[tid] = H[(size_t)(bh * 16 + i) * 512 + tid];
    Zl[tid] = zcol[(size_t)(b * 16 + i) * 512 + tid];
    __syncthreads();
    float g[8], h[8], z[8];
    #pragma unroll
    for (int j = 0; j < 8; ++j){
      g[j] = Gl[lane * 8 + j]; h[j] = Hl[lane * 8 + j]; z[j] = Zl[lane * 8 + j];
    }
    #pragma unroll
    for (int sl = 0; sl < 8; ++sl){
      int s = sb * 64 + w * 8 + sl;
      float y = Zl[s];
      float e[8]; float dsum = 0.f, rsum = 0.f;
      #pragma unroll
      for (int j = 0; j < 8; ++j){
        e[j] = __expf(fmaf(y, g[j], h[j]));
        dsum += e[j];
        rsum += e[j] * z[j];
      }
      #pragma unroll
      for (int off = 32; off >= 1; off >>= 1){
        dsum += __shfl_xor(dsum, off, 64);
        rsum += __shfl_xor(rsum, off, 64);
      }
      float inv = 1.0f / dsum;
      #pragma unroll
      for (int j = 0; j < 8; ++j) Pacc[sl][j] += e[j] * inv;
      if (lane == 0) R[(size_t)(bh * 512 + s) * 16 + i] = rsum * inv;
    }
    __syncthreads();
  }
  #pragma unroll
  for (int sl = 0; sl < 8; ++sl){
    int s = sb * 64 + w * 8 + sl;
    unsigned int p0 = (unsigned int)f2bf(Pacc[sl][0]) | ((unsigned int)f2bf(Pacc[sl][1]) << 16);
    unsigned int p1 = (unsigned int)f2bf(Pacc[sl][2]) | ((unsigned int)f2bf(Pacc[sl][3]) << 16);
    unsigned int p2 = (unsigned int)f2bf(Pacc[sl][4]) | ((unsigned int)f2bf(Pacc[sl][5]) << 16);
    unsigned int p3 = (unsigned int)f2bf(Pacc[sl][6]) | ((unsigned int)f2bf(Pacc[sl][7]) << 16);
    uint4 pk; pk.x = p0; pk.y = p1; pk.z = p2; pk.w = p3;
    *reinterpret_cast<uint4*>(Pb + (size_t)(bhl * 512 + s) * 512 + lane * 8) = pk;
  }
}

// ---------------- PV: O = Pbar @ Vf - correction; write Ob bf16 ----------------
// grid: 32(bhl)*8(st)*4(dt) blocks, 256 thr (4 waves, wave = 16-row m sub-tile)
__global__ __launch_bounds__(256) void k_pv(const unsigned short* __restrict__ Pb,
    const unsigned short* __restrict__ VfT, const float* __restrict__ R,
    const float* __restrict__ W_in, int bh0, unsigned short* __restrict__ Ob){
  int bid = blockIdx.x;
  int bhl = bid >> 5; int st = (bid >> 2) & 7; int dt = bid & 3;
  int bh = bh0 + bhl; int b = bh >> 3, h = bh & 7;
  int w = threadIdx.x >> 6, l = threadIdx.x & 63;
  int kb = l >> 4, ln = l & 15;
  int s0 = st * 64 + w * 16; int d0 = dt * 16;

  __shared__ float Rl[64][17];
  __shared__ float Wvl[16][17];
  int tid = threadIdx.x;
  for (int idx = tid; idx < 1024; idx += 256){
    int sl = idx >> 4, i = idx & 15;
    Rl[sl][i] = R[(size_t)(bh * 512 + st * 64 + sl) * 16 + i];
  }
  { int dl = tid >> 4, i = tid & 15;
    Wvl[dl][i] = W_in[(size_t)(1024 + h * 64 + d0 + dl) * DMODEL + i]; }
  __syncthreads();

  const unsigned short* ap = Pb + (size_t)(bhl * 512 + s0 + ln) * 512 + kb * 8;
  const unsigned short* bp = VfT + (size_t)b * (DMODEL * S_LEN) + (size_t)(h * 64 + d0 + ln) * S_LEN + kb * 8;
  f32x4 acc = {0.f, 0.f, 0.f, 0.f};
  #pragma unroll
  for (int k0 = 0; k0 < S_LEN; k0 += 32){
    s16x8 a = *reinterpret_cast<const s16x8*>(ap + k0);
    s16x8 bb = *reinterpret_cast<const s16x8*>(bp + k0);
    acc = __builtin_amdgcn_mfma_f32_16x16x32_bf16(a, bb, acc, 0, 0, 0);
  }
  #pragma unroll
  for (int r = 0; r < 4; ++r){
    int m = s0 + kb * 4 + r;        // s index
    int ml = m - st * 64;
    float corr = 0.f;
    #pragma unroll
    for (int i = 0; i < 16; ++i) corr += Rl[ml][i] * Wvl[ln][i];
    float v = acc[r] - corr;
    Ob[(size_t)(m * BATCH + b) * DMODEL + h * 64 + d0 + ln] = f2bf(v);
  }
}

// ---------------- out-proj: out = Ob @ W_out^T + 16*b_out (f32 out) ----------------
__global__ __launch_bounds__(256) void k_out(const unsigned short* __restrict__ Ob,
    const unsigned short* __restrict__ Wob, const float* __restrict__ b_out,
    float* __restrict__ out){
  int w = threadIdx.x >> 6, l = threadIdx.x & 63;
  int kb = l >> 4, ln = l & 15;
  int m0 = blockIdx.x * 64 + w * 16;
  int n  = blockIdx.y * 16 + ln;
  const unsigned short* ap = Ob + (size_t)(m0 + ln) * DMODEL + kb * 8;
  const unsigned short* bp = Wob + (size_t)n * DMODEL + kb * 8;
  f32x4 acc = {0.f, 0.f, 0.f, 0.f};
  #pragma unroll
  for (int k0 = 0; k0 < DMODEL; k0 += 32){
    s16x8 a = *reinterpret_cast<const s16x8*>(ap + k0);
    s16x8 b = *reinterpret_cast<const s16x8*>(bp + k0);
    acc = __builtin_amdgcn_mfma_f32_16x16x32_bf16(a, b, acc, 0, 0, 0);
  }
  float bias = 16.0f * b_out[n];
  #pragma unroll
  for (int r = 0; r < 4; ++r){
    out[(size_t)(m0 + kb * 4 + r) * DMODEL + n] = acc[r] + bias;
  }
}

extern "C" void kernel_launch(void* const* d_in, const int* in_sizes, int n_in,
                              void* d_out, int out_size, void* d_ws, size_t ws_size,
                              hipStream_t stream) {
  const float* x     = (const float*)d_in[0];
  const float* W_in  = (const float*)d_in[1];
  const float* b_in  = (const float*)d_in[2];
  const float* W_out = (const float*)d_in[3];
  const float* b_out = (const float*)d_in[4];
  float* out = (float*)d_out;

  size_t off = 0;
  char* base = (char*)d_ws;
  auto alloc = [&](size_t bytes) -> void* {
    void* p = base + off;
    off += (bytes + 255) & ~(size_t)255;
    return p;
  };
  unsigned short* xb   = (unsigned short*)alloc(8388608);    // x bf16
  unsigned short* Winb = (unsigned short*)alloc(1572864);    // W_in bf16
  unsigned short* Wob  = (unsigned short*)alloc(524288);     // W_out bf16
  float*          zcol = (float*)alloc(524288);              // [b][i][t]
  float*          Kf   = (float*)alloc(16777216);            // [r][d] f32
  unsigned short* Vfb  = (unsigned short*)alloc(8388608);    // [r][d] bf16
  unsigned short* VfT  = (unsigned short*)alloc(8388608);    // [b][d][t] bf16
  float*          G    = (float*)alloc(4194304);             // [bh][i][t]
  float*          H    = (float*)alloc(4194304);             // [bh][i][t]
  float*          R    = (float*)alloc(4194304);             // [bh][s][i]
  unsigned short* Ob   = (unsigned short*)alloc(8388608);    // [r][d] bf16
  unsigned short* Pb   = (unsigned short*)alloc(16777216);   // chunk: [32 bh][s][t] bf16

  k_cvt<<<4096, 256, 0, stream>>>(x, xb);
  k_cvt<<<768, 256, 0, stream>>>(W_in, Winb);
  k_cvt<<<256, 256, 0, stream>>>(W_out, Wob);
  k_zcol<<<512, 256, 0, stream>>>(x, zcol);

  { dim3 g(128, 64); k_kvgemm<<<g, 256, 0, stream>>>(xb, Winb, b_in, Kf, Vfb); }
  { dim3 g(16, 16, 16); k_tr<<<g, 256, 0, stream>>>(Vfb, VfT); }
  k_gh<<<128, 512, 0, stream>>>(W_in, b_in, Kf, zcol, G, H);

  for (int c = 0; c < 4; ++c){
    k_sm<<<256, 512, 0, stream>>>(G, H, zcol, c * 32, R, Pb);
    k_pv<<<1024, 256, 0, stream>>>(Pb, VfT, R, W_in, c * 32, Ob);
  }

  { dim3 g(128, 32); k_out<<<g, 256, 0, stream>>>(Ob, Wob, b_out, out); }
}

// Round 2
// 400.978 us; speedup vs baseline: 1.3781x; 1.3781x over previous
//
#include <hip/hip_runtime.h>

// Problem constants
#define S_LEN 512
#define BATCH 16
#define DMODEL 512
#define NHEAD 8
#define DH 64
#define NI 16      // loop count = x.shape[1] = 16 channel iterations

typedef float f32x4 __attribute__((ext_vector_type(4)));
typedef short s16x8 __attribute__((ext_vector_type(8)));

__device__ __forceinline__ unsigned short f2bf(float f){
  unsigned int u = __float_as_uint(f);
  u += 0x7FFFu + ((u >> 16) & 1u);   // RNE
  return (unsigned short)(u >> 16);
}

// async global->LDS 16B copy; lptr must be wave-uniform (HW adds lane*16)
__device__ __forceinline__ void async16(const unsigned short* g, unsigned short* l){
  __builtin_amdgcn_global_load_lds(
      (const __attribute__((address_space(1))) unsigned int*)g,
      (__attribute__((address_space(3))) unsigned int*)l, 16, 0, 0);
}

// ---------------- convert f32 -> bf16 (4 elems/thread) ----------------
__global__ void k_cvt(const float* __restrict__ src, unsigned short* __restrict__ dst){
  int t = blockIdx.x * 256 + threadIdx.x;
  float4 v = reinterpret_cast<const float4*>(src)[t];
  ushort4 o;
  o.x = f2bf(v.x); o.y = f2bf(v.y); o.z = f2bf(v.z); o.w = f2bf(v.w);
  reinterpret_cast<ushort4*>(dst)[t] = o;
}

// ---------------- zcol[b][i][t] = x[t][b][i] ----------------
__global__ void k_zcol(const float* __restrict__ x, float* __restrict__ zcol){
  int tid = blockIdx.x * 256 + threadIdx.x;     // 16*16*512 = 131072
  int t = tid & 511; int bi = tid >> 9; int b = bi >> 4; int i = bi & 15;
  zcol[tid] = x[(size_t)(t * BATCH + b) * DMODEL + i];
}

// ---------------- K/V projection, m97-style 128x128 tile ----------------
// C[m][n] = sum_k xb[m][k] * Winb[512+n][k] + b_in[512+n]; n<512 -> Kf f32, else Vfb bf16
__global__ __launch_bounds__(256) void k_kv2(const unsigned short* __restrict__ xb,
    const unsigned short* __restrict__ Winb, const float* __restrict__ b_in,
    float* __restrict__ Kf, unsigned short* __restrict__ Vfb){
  __shared__ unsigned short As[2][128 * 32];
  __shared__ unsigned short Bs[2][128 * 32];
  int tid = threadIdx.x;
  int w = tid >> 6, l = tid & 63;
  int ln = l & 15, kb = l >> 4;
  int wr = w >> 1, wc = w & 1;
  int m0 = blockIdx.x * 128;
  int n0 = blockIdx.y * 128;
  const unsigned short* Brow = Winb + (size_t)512 * DMODEL;

  f32x4 acc[4][4];
  #pragma unroll
  for (int mi = 0; mi < 4; ++mi)
    #pragma unroll
    for (int nj = 0; nj < 4; ++nj) acc[mi][nj] = (f32x4){0.f,0.f,0.f,0.f};

  int c0 = tid, c1 = 256 + tid;
  int r0 = c0 >> 2, q0 = c0 & 3, r1 = c1 >> 2, q1 = c1 & 3;
  // wave-uniform LDS chunk bases (ushort units)
  int lb0 = (w * 64) * 8, lb1 = (256 + w * 64) * 8;

  #define STAGE_KV(kt, buf) do { int k0 = (kt) * 32;                                   \
    async16(xb   + (size_t)(m0 + r0) * DMODEL + k0 + q0 * 8, &As[buf][lb0]);           \
    async16(xb   + (size_t)(m0 + r1) * DMODEL + k0 + q1 * 8, &As[buf][lb1]);           \
    async16(Brow + (size_t)(n0 + r0) * DMODEL + k0 + q0 * 8, &Bs[buf][lb0]);           \
    async16(Brow + (size_t)(n0 + r1) * DMODEL + k0 + q1 * 8, &Bs[buf][lb1]);           \
  } while(0)

  STAGE_KV(0, 0);
  __syncthreads();
  int cur = 0;
  for (int kt = 0; kt < 16; ++kt){
    if (kt < 15) STAGE_KV(kt + 1, cur ^ 1);
    const unsigned short* Ab = &As[cur][(wr * 64 + ln) * 32 + kb * 8];
    const unsigned short* Bb = &Bs[cur][(wc * 64 + ln) * 32 + kb * 8];
    s16x8 af[4], bf[4];
    #pragma unroll
    for (int mi = 0; mi < 4; ++mi) af[mi] = *reinterpret_cast<const s16x8*>(Ab + mi * 16 * 32);
    #pragma unroll
    for (int nj = 0; nj < 4; ++nj) bf[nj] = *reinterpret_cast<const s16x8*>(Bb + nj * 16 * 32);
    #pragma unroll
    for (int mi = 0; mi < 4; ++mi)
      #pragma unroll
      for (int nj = 0; nj < 4; ++nj)
        acc[mi][nj] = __builtin_amdgcn_mfma_f32_16x16x32_bf16(af[mi], bf[nj], acc[mi][nj], 0, 0, 0);
    __syncthreads();
    cur ^= 1;
  }
  #undef STAGE_KV

  #pragma unroll
  for (int nj = 0; nj < 4; ++nj){
    int n = n0 + wc * 64 + nj * 16 + ln;
    float bias = b_in[512 + n];
    #pragma unroll
    for (int mi = 0; mi < 4; ++mi){
      #pragma unroll
      for (int r = 0; r < 4; ++r){
        int m = m0 + wr * 64 + mi * 16 + kb * 4 + r;
        float v = acc[mi][nj][r] + bias;
        if (n < DMODEL) Kf[(size_t)m * DMODEL + n] = v;
        else            Vfb[(size_t)m * DMODEL + (n - DMODEL)] = f2bf(v);
      }
    }
  }
}

// ---------------- transpose Vfb [t*B+b][d] -> VfT [b][d][t] (bf16) ----------------
__global__ void k_tr(const unsigned short* __restrict__ Vfb, unsigned short* __restrict__ VfT){
  __shared__ unsigned short tile[32][34];
  int b = blockIdx.z; int t0 = blockIdx.x * 32; int d0 = blockIdx.y * 32;
  int tx = threadIdx.x & 31, ty = threadIdx.x >> 5;   // 32 x 8
  #pragma unroll
  for (int k = 0; k < 4; ++k){
    int row = ty + 8 * k;
    tile[row][tx] = Vfb[(size_t)((t0 + row) * BATCH + b) * DMODEL + d0 + tx];
  }
  __syncthreads();
  #pragma unroll
  for (int k = 0; k < 4; ++k){
    int row = ty + 8 * k;
    VfT[(size_t)b * (DMODEL * S_LEN) + (size_t)(d0 + row) * S_LEN + t0 + tx] = tile[tx][row];
  }
}

// ---------------- G,H precompute: per (b,h): G[bh][i][t], H[bh][i][t] ----------------
__global__ __launch_bounds__(512) void k_gh(const float* __restrict__ W_in,
    const float* __restrict__ b_in, const float* __restrict__ Kf,
    const float* __restrict__ zcol, float* __restrict__ G, float* __restrict__ H){
  int bh = blockIdx.x; int b = bh >> 3, h = bh & 7;
  __shared__ float u[64][17];     // u[d][i] = Wq[h*64+d][i]
  __shared__ float cvec[64];      // bq[hslice]
  __shared__ float alpha[16], beta[16];
  int tid = threadIdx.x;
  for (int idx = tid; idx < 1024; idx += 512){
    int d = idx >> 4, i = idx & 15;
    u[d][i] = W_in[(size_t)(h * 64 + d) * DMODEL + i];
  }
  if (tid < 64) cvec[tid] = b_in[h * 64 + tid];
  __syncthreads();
  if (tid < 16){
    float a = 0.f, be = 0.f;
    for (int d = 0; d < 64; ++d){
      float wk = W_in[(size_t)(512 + h * 64 + d) * DMODEL + tid];
      a  += u[d][tid] * wk;
      be += cvec[d] * wk;
    }
    alpha[tid] = a; beta[tid] = be;
  }
  __syncthreads();
  int t = tid;  // 0..511
  float K[64];
  const float* kp = Kf + (size_t)(t * BATCH + b) * DMODEL + h * 64;
  #pragma unroll
  for (int d = 0; d < 64; d += 4){
    float4 v = *reinterpret_cast<const float4*>(kp + d);
    K[d] = v.x; K[d+1] = v.y; K[d+2] = v.z; K[d+3] = v.w;
  }
  float Bt = 0.f;
  #pragma unroll
  for (int d = 0; d < 64; ++d) Bt += cvec[d] * K[d];
  for (int i = 0; i < 16; ++i){
    float A = 0.f;
    #pragma unroll
    for (int d = 0; d < 64; ++d) A += u[d][i] * K[d];
    float z = zcol[(size_t)(b * 16 + i) * 512 + t];
    G[(size_t)(bh * 16 + i) * 512 + t] = (A  - alpha[i] * z) * 0.125f;
    H[(size_t)(bh * 16 + i) * 512 + t] = (Bt - beta[i]  * z) * 0.125f;
  }
}

// ---------------- softmax accumulate: Pbar rows + r_i ----------------
__global__ __launch_bounds__(512) void k_sm(const float* __restrict__ G,
    const float* __restrict__ H, const float* __restrict__ zcol, int bh0,
    float* __restrict__ R, unsigned short* __restrict__ Pb){
  int blk = blockIdx.x; int bhl = blk >> 3; int sb = blk & 7;
  int bh = bh0 + bhl; int b = bh >> 3;
  __shared__ float Gl[512], Hl[512], Zl[512];
  int tid = threadIdx.x, lane = tid & 63, w = tid >> 6;
  float Pacc[8][8];
  #pragma unroll
  for (int a = 0; a < 8; ++a)
    #pragma unroll
    for (int j = 0; j < 8; ++j) Pacc[a][j] = 0.f;

  for (int i = 0; i < NI; ++i){
    Gl[tid] = G[(size_t)(bh * 16 + i) * 512 + tid];
    Hl[tid] = H[(size_t)(bh * 16 + i) * 512 + tid];
    Zl[tid] = zcol[(size_t)(b * 16 + i) * 512 + tid];
    __syncthreads();
    float g[8], h[8], z[8];
    #pragma unroll
    for (int j = 0; j < 8; ++j){
      g[j] = Gl[lane * 8 + j]; h[j] = Hl[lane * 8 + j]; z[j] = Zl[lane * 8 + j];
    }
    #pragma unroll
    for (int sl = 0; sl < 8; ++sl){
      int s = sb * 64 + w * 8 + sl;
      float y = Zl[s];
      float e[8]; float dsum = 0.f, rsum = 0.f;
      #pragma unroll
      for (int j = 0; j < 8; ++j){
        e[j] = __expf(fmaf(y, g[j], h[j]));
        dsum += e[j];
        rsum += e[j] * z[j];
      }
      #pragma unroll
      for (int off = 32; off >= 1; off >>= 1){
        dsum += __shfl_xor(dsum, off, 64);
        rsum += __shfl_xor(rsum, off, 64);
      }
      float inv = 1.0f / dsum;
      #pragma unroll
      for (int j = 0; j < 8; ++j) Pacc[sl][j] += e[j] * inv;
      if (lane == 0) R[(size_t)(bh * 512 + s) * 16 + i] = rsum * inv;
    }
    __syncthreads();
  }
  #pragma unroll
  for (int sl = 0; sl < 8; ++sl){
    int s = sb * 64 + w * 8 + sl;
    unsigned int p0 = (unsigned int)f2bf(Pacc[sl][0]) | ((unsigned int)f2bf(Pacc[sl][1]) << 16);
    unsigned int p1 = (unsigned int)f2bf(Pacc[sl][2]) | ((unsigned int)f2bf(Pacc[sl][3]) << 16);
    unsigned int p2 = (unsigned int)f2bf(Pacc[sl][4]) | ((unsigned int)f2bf(Pacc[sl][5]) << 16);
    unsigned int p3 = (unsigned int)f2bf(Pacc[sl][6]) | ((unsigned int)f2bf(Pacc[sl][7]) << 16);
    uint4 pk; pk.x = p0; pk.y = p1; pk.z = p2; pk.w = p3;
    *reinterpret_cast<uint4*>(Pb + (size_t)(bhl * 512 + s) * 512 + lane * 8) = pk;
  }
}

// ---------------- PV: O = Pbar @ Vf - R@Wv^T; 128x64 tile, LDS-staged ----------------
__global__ __launch_bounds__(256) void k_pv2(const unsigned short* __restrict__ Pb,
    const unsigned short* __restrict__ VfT, const float* __restrict__ R,
    const float* __restrict__ W_in, int bh0, unsigned short* __restrict__ Ob){
  __shared__ unsigned short As[2][128 * 32];
  __shared__ unsigned short Bs[2][64 * 32];
  __shared__ float Rl[128][17];
  __shared__ float Wvl[64][17];
  int bid = blockIdx.x;
  int bhl = bid >> 2, st = bid & 3;
  int bh = bh0 + bhl; int b = bh >> 3, h = bh & 7;
  int tid = threadIdx.x;
  int w = tid >> 6, l = tid & 63;
  int ln = l & 15, kb = l >> 4;
  int wr = w >> 1, wc = w & 1;

  const unsigned short* Abase = Pb + (size_t)(bhl * 512 + st * 128) * S_LEN;
  const unsigned short* Bbase = VfT + (size_t)b * (DMODEL * S_LEN) + (size_t)(h * 64) * S_LEN;

  for (int idx = tid; idx < 128 * 16; idx += 256){
    int sl = idx >> 4, i = idx & 15;
    Rl[sl][i] = R[(size_t)(bh * 512 + st * 128 + sl) * 16 + i];
  }
  for (int idx = tid; idx < 64 * 16; idx += 256){
    int dl = idx >> 4, i = idx & 15;
    Wvl[dl][i] = W_in[(size_t)(1024 + h * 64 + dl) * DMODEL + i];
  }

  f32x4 acc[4][2];
  #pragma unroll
  for (int mi = 0; mi < 4; ++mi)
    #pragma unroll
    for (int nj = 0; nj < 2; ++nj) acc[mi][nj] = (f32x4){0.f,0.f,0.f,0.f};

  int c0 = tid, c1 = 256 + tid;
  int r0 = c0 >> 2, q0 = c0 & 3, r1 = c1 >> 2, q1 = c1 & 3;
  int lb0 = (w * 64) * 8, lb1 = (256 + w * 64) * 8;

  #define STAGE_PV(kt, buf) do { int k0 = (kt) * 32;                              \
    async16(Abase + (size_t)r0 * S_LEN + k0 + q0 * 8, &As[buf][lb0]);             \
    async16(Abase + (size_t)r1 * S_LEN + k0 + q1 * 8, &As[buf][lb1]);             \
    async16(Bbase + (size_t)r0 * S_LEN + k0 + q0 * 8, &Bs[buf][lb0]);             \
  } while(0)

  STAGE_PV(0, 0);
  __syncthreads();
  int cur = 0;
  for (int kt = 0; kt < 16; ++kt){
    if (kt < 15) STAGE_PV(kt + 1, cur ^ 1);
    const unsigned short* Ab = &As[cur][(wr * 64 + ln) * 32 + kb * 8];
    const unsigned short* Bb = &Bs[cur][(wc * 32 + ln) * 32 + kb * 8];
    s16x8 af[4], bf[2];
    #pragma unroll
    for (int mi = 0; mi < 4; ++mi) af[mi] = *reinterpret_cast<const s16x8*>(Ab + mi * 16 * 32);
    #pragma unroll
    for (int nj = 0; nj < 2; ++nj) bf[nj] = *reinterpret_cast<const s16x8*>(Bb + nj * 16 * 32);
    #pragma unroll
    for (int mi = 0; mi < 4; ++mi)
      #pragma unroll
      for (int nj = 0; nj < 2; ++nj)
        acc[mi][nj] = __builtin_amdgcn_mfma_f32_16x16x32_bf16(af[mi], bf[nj], acc[mi][nj], 0, 0, 0);
    __syncthreads();
    cur ^= 1;
  }
  #undef STAGE_PV

  #pragma unroll
  for (int nj = 0; nj < 2; ++nj){
    int dl = wc * 32 + nj * 16 + ln;
    #pragma unroll
    for (int mi = 0; mi < 4; ++mi){
      #pragma unroll
      for (int r = 0; r < 4; ++r){
        int ml = wr * 64 + mi * 16 + kb * 4 + r;
        int m = st * 128 + ml;   // s index
        float corr = 0.f;
        #pragma unroll
        for (int i = 0; i < 16; ++i) corr += Rl[ml][i] * Wvl[dl][i];
        float v = acc[mi][nj][r] - corr;
        Ob[(size_t)(m * BATCH + b) * DMODEL + h * 64 + dl] = f2bf(v);
      }
    }
  }
}

// ---------------- out-proj: out = Ob @ W_out^T + 16*b_out, 128x128 tile ----------------
__global__ __launch_bounds__(256) void k_out2(const unsigned short* __restrict__ Ob,
    const unsigned short* __restrict__ Wob, const float* __restrict__ b_out,
    float* __restrict__ out){
  __shared__ unsigned short As[2][128 * 32];
  __shared__ unsigned short Bs[2][128 * 32];
  int tid = threadIdx.x;
  int w = tid >> 6, l = tid & 63;
  int ln = l & 15, kb = l >> 4;
  int wr = w >> 1, wc = w & 1;
  int m0 = blockIdx.x * 128;
  int n0 = blockIdx.y * 128;

  f32x4 acc[4][4];
  #pragma unroll
  for (int mi = 0; mi < 4; ++mi)
    #pragma unroll
    for (int nj = 0; nj < 4; ++nj) acc[mi][nj] = (f32x4){0.f,0.f,0.f,0.f};

  int c0 = tid, c1 = 256 + tid;
  int r0 = c0 >> 2, q0 = c0 & 3, r1 = c1 >> 2, q1 = c1 & 3;
  int lb0 = (w * 64) * 8, lb1 = (256 + w * 64) * 8;

  #define STAGE_O(kt, buf) do { int k0 = (kt) * 32;                                    \
    async16(Ob  + (size_t)(m0 + r0) * DMODEL + k0 + q0 * 8, &As[buf][lb0]);            \
    async16(Ob  + (size_t)(m0 + r1) * DMODEL + k0 + q1 * 8, &As[buf][lb1]);            \
    async16(Wob + (size_t)(n0 + r0) * DMODEL + k0 + q0 * 8, &Bs[buf][lb0]);            \
    async16(Wob + (size_t)(n0 + r1) * DMODEL + k0 + q1 * 8, &Bs[buf][lb1]);            \
  } while(0)

  STAGE_O(0, 0);
  __syncthreads();
  int cur = 0;
  for (int kt = 0; kt < 16; ++kt){
    if (kt < 15) STAGE_O(kt + 1, cur ^ 1);
    const unsigned short* Ab = &As[cur][(wr * 64 + ln) * 32 + kb * 8];
    const unsigned short* Bb = &Bs[cur][(wc * 64 + ln) * 32 + kb * 8];
    s16x8 af[4], bf[4];
    #pragma unroll
    for (int mi = 0; mi < 4; ++mi) af[mi] = *reinterpret_cast<const s16x8*>(Ab + mi * 16 * 32);
    #pragma unroll
    for (int nj = 0; nj < 4; ++nj) bf[nj] = *reinterpret_cast<const s16x8*>(Bb + nj * 16 * 32);
    #pragma unroll
    for (int mi = 0; mi < 4; ++mi)
      #pragma unroll
      for (int nj = 0; nj < 4; ++nj)
        acc[mi][nj] = __builtin_amdgcn_mfma_f32_16x16x32_bf16(af[mi], bf[nj], acc[mi][nj], 0, 0, 0);
    __syncthreads();
    cur ^= 1;
  }
  #undef STAGE_O

  #pragma unroll
  for (int nj = 0; nj < 4; ++nj){
    int n = n0 + wc * 64 + nj * 16 + ln;
    float bias = 16.0f * b_out[n];
    #pragma unroll
    for (int mi = 0; mi < 4; ++mi){
      #pragma unroll
      for (int r = 0; r < 4; ++r){
        int m = m0 + wr * 64 + mi * 16 + kb * 4 + r;
        out[(size_t)m * DMODEL + n] = acc[mi][nj][r] + bias;
      }
    }
  }
}

extern "C" void kernel_launch(void* const* d_in, const int* in_sizes, int n_in,
                              void* d_out, int out_size, void* d_ws, size_t ws_size,
                              hipStream_t stream) {
  const float* x     = (const float*)d_in[0];
  const float* W_in  = (const float*)d_in[1];
  const float* b_in  = (const float*)d_in[2];
  const float* W_out = (const float*)d_in[3];
  const float* b_out = (const float*)d_in[4];
  float* out = (float*)d_out;

  size_t off = 0;
  char* base = (char*)d_ws;
  auto alloc = [&](size_t bytes) -> void* {
    void* p = base + off;
    off += (bytes + 255) & ~(size_t)255;
    return p;
  };
  unsigned short* xb   = (unsigned short*)alloc(8388608);    // x bf16
  unsigned short* Winb = (unsigned short*)alloc(1572864);    // W_in bf16
  unsigned short* Wob  = (unsigned short*)alloc(524288);     // W_out bf16
  float*          zcol = (float*)alloc(524288);              // [b][i][t]
  float*          Kf   = (float*)alloc(16777216);            // [r][d] f32
  unsigned short* Vfb  = (unsigned short*)alloc(8388608);    // [r][d] bf16
  unsigned short* VfT  = (unsigned short*)alloc(8388608);    // [b][d][t] bf16
  float*          G    = (float*)alloc(4194304);             // [bh][i][t]
  float*          H    = (float*)alloc(4194304);             // [bh][i][t]
  float*          R    = (float*)alloc(4194304);             // [bh][s][i]
  unsigned short* Ob   = (unsigned short*)alloc(8388608);    // [r][d] bf16
  unsigned short* Pb   = (unsigned short*)alloc(16777216);   // chunk: [32 bh][s][t] bf16

  k_cvt<<<4096, 256, 0, stream>>>(x, xb);
  k_cvt<<<768, 256, 0, stream>>>(W_in, Winb);
  k_cvt<<<256, 256, 0, stream>>>(W_out, Wob);
  k_zcol<<<512, 256, 0, stream>>>(x, zcol);

  { dim3 g(64, 8); k_kv2<<<g, 256, 0, stream>>>(xb, Winb, b_in, Kf, Vfb); }
  { dim3 g(16, 16, 16); k_tr<<<g, 256, 0, stream>>>(Vfb, VfT); }
  k_gh<<<128, 512, 0, stream>>>(W_in, b_in, Kf, zcol, G, H);

  for (int c = 0; c < 4; ++c){
    k_sm<<<256, 512, 0, stream>>>(G, H, zcol, c * 32, R, Pb);
    k_pv2<<<128, 256, 0, stream>>>(Pb, VfT, R, W_in, c * 32, Ob);
  }

  { dim3 g(64, 4); k_out2<<<g, 256, 0, stream>>>(Ob, Wob, b_out, out); }
}

// Round 3
// 291.164 us; speedup vs baseline: 1.8979x; 1.3772x over previous
//
#include <hip/hip_runtime.h>

// Problem constants
#define S_LEN 512
#define BATCH 16
#define DMODEL 512
#define NHEAD 8
#define DH 64
#define NI 16      // loop count = x.shape[1] = 16 channel iterations

typedef float f32x4 __attribute__((ext_vector_type(4)));
typedef short s16x8 __attribute__((ext_vector_type(8)));

__device__ __forceinline__ unsigned short f2bf(float f){
  unsigned int u = __float_as_uint(f);
  u += 0x7FFFu + ((u >> 16) & 1u);   // RNE
  return (unsigned short)(u >> 16);
}

// async global->LDS 16B copy; lptr must be wave-uniform (HW adds lane*16)
__device__ __forceinline__ void async16(const unsigned short* g, unsigned short* l){
  __builtin_amdgcn_global_load_lds(
      (const __attribute__((address_space(1))) unsigned int*)g,
      (__attribute__((address_space(3))) unsigned int*)l, 16, 0, 0);
}

// ---------------- convert f32 -> bf16 (4 elems/thread) ----------------
__global__ void k_cvt(const float* __restrict__ src, unsigned short* __restrict__ dst){
  int t = blockIdx.x * 256 + threadIdx.x;
  float4 v = reinterpret_cast<const float4*>(src)[t];
  ushort4 o;
  o.x = f2bf(v.x); o.y = f2bf(v.y); o.z = f2bf(v.z); o.w = f2bf(v.w);
  reinterpret_cast<ushort4*>(dst)[t] = o;
}

// ---------------- zcol[b][i][t] = x[t][b][i] ----------------
__global__ void k_zcol(const float* __restrict__ x, float* __restrict__ zcol){
  int tid = blockIdx.x * 256 + threadIdx.x;     // 16*16*512 = 131072
  int t = tid & 511; int bi = tid >> 9; int b = bi >> 4; int i = bi & 15;
  zcol[tid] = x[(size_t)(t * BATCH + b) * DMODEL + i];
}

// ---------------- K/V projection, m97-style 128x128 tile ----------------
__global__ __launch_bounds__(256) void k_kv2(const unsigned short* __restrict__ xb,
    const unsigned short* __restrict__ Winb, const float* __restrict__ b_in,
    float* __restrict__ Kf, unsigned short* __restrict__ Vfb){
  __shared__ unsigned short As[2][128 * 32];
  __shared__ unsigned short Bs[2][128 * 32];
  int tid = threadIdx.x;
  int w = tid >> 6, l = tid & 63;
  int ln = l & 15, kb = l >> 4;
  int wr = w >> 1, wc = w & 1;
  int m0 = blockIdx.x * 128;
  int n0 = blockIdx.y * 128;
  const unsigned short* Brow = Winb + (size_t)512 * DMODEL;

  f32x4 acc[4][4];
  #pragma unroll
  for (int mi = 0; mi < 4; ++mi)
    #pragma unroll
    for (int nj = 0; nj < 4; ++nj) acc[mi][nj] = (f32x4){0.f,0.f,0.f,0.f};

  int c0 = tid, c1 = 256 + tid;
  int r0 = c0 >> 2, q0 = c0 & 3, r1 = c1 >> 2, q1 = c1 & 3;
  int lb0 = (w * 64) * 8, lb1 = (256 + w * 64) * 8;

  #define STAGE_KV(kt, buf) do { int k0 = (kt) * 32;                                   \
    async16(xb   + (size_t)(m0 + r0) * DMODEL + k0 + q0 * 8, &As[buf][lb0]);           \
    async16(xb   + (size_t)(m0 + r1) * DMODEL + k0 + q1 * 8, &As[buf][lb1]);           \
    async16(Brow + (size_t)(n0 + r0) * DMODEL + k0 + q0 * 8, &Bs[buf][lb0]);           \
    async16(Brow + (size_t)(n0 + r1) * DMODEL + k0 + q1 * 8, &Bs[buf][lb1]);           \
  } while(0)

  STAGE_KV(0, 0);
  __syncthreads();
  int cur = 0;
  for (int kt = 0; kt < 16; ++kt){
    if (kt < 15) STAGE_KV(kt + 1, cur ^ 1);
    const unsigned short* Ab = &As[cur][(wr * 64 + ln) * 32 + kb * 8];
    const unsigned short* Bb = &Bs[cur][(wc * 64 + ln) * 32 + kb * 8];
    s16x8 af[4], bf[4];
    #pragma unroll
    for (int mi = 0; mi < 4; ++mi) af[mi] = *reinterpret_cast<const s16x8*>(Ab + mi * 16 * 32);
    #pragma unroll
    for (int nj = 0; nj < 4; ++nj) bf[nj] = *reinterpret_cast<const s16x8*>(Bb + nj * 16 * 32);
    #pragma unroll
    for (int mi = 0; mi < 4; ++mi)
      #pragma unroll
      for (int nj = 0; nj < 4; ++nj)
        acc[mi][nj] = __builtin_amdgcn_mfma_f32_16x16x32_bf16(af[mi], bf[nj], acc[mi][nj], 0, 0, 0);
    __syncthreads();
    cur ^= 1;
  }
  #undef STAGE_KV

  #pragma unroll
  for (int nj = 0; nj < 4; ++nj){
    int n = n0 + wc * 64 + nj * 16 + ln;
    float bias = b_in[512 + n];
    #pragma unroll
    for (int mi = 0; mi < 4; ++mi){
      #pragma unroll
      for (int r = 0; r < 4; ++r){
        int m = m0 + wr * 64 + mi * 16 + kb * 4 + r;
        float v = acc[mi][nj][r] + bias;
        if (n < DMODEL) Kf[(size_t)m * DMODEL + n] = v;
        else            Vfb[(size_t)m * DMODEL + (n - DMODEL)] = f2bf(v);
      }
    }
  }
}

// ---------------- transpose Vfb [t*B+b][d] -> VfT [b][d][t] (bf16) ----------------
__global__ void k_tr(const unsigned short* __restrict__ Vfb, unsigned short* __restrict__ VfT){
  __shared__ unsigned short tile[32][34];
  int b = blockIdx.z; int t0 = blockIdx.x * 32; int d0 = blockIdx.y * 32;
  int tx = threadIdx.x & 31, ty = threadIdx.x >> 5;   // 32 x 8
  #pragma unroll
  for (int k = 0; k < 4; ++k){
    int row = ty + 8 * k;
    tile[row][tx] = Vfb[(size_t)((t0 + row) * BATCH + b) * DMODEL + d0 + tx];
  }
  __syncthreads();
  #pragma unroll
  for (int k = 0; k < 4; ++k){
    int row = ty + 8 * k;
    VfT[(size_t)b * (DMODEL * S_LEN) + (size_t)(d0 + row) * S_LEN + t0 + tx] = tile[tx][row];
  }
}

// ---------------- G,H precompute: per (b,h): G[bh][i][t], H[bh][i][t] ----------------
__global__ __launch_bounds__(512) void k_gh(const float* __restrict__ W_in,
    const float* __restrict__ b_in, const float* __restrict__ Kf,
    const float* __restrict__ zcol, float* __restrict__ G, float* __restrict__ H){
  int bh = blockIdx.x; int b = bh >> 3, h = bh & 7;
  __shared__ float u[64][17];     // u[d][i] = Wq[h*64+d][i]
  __shared__ float cvec[64];      // bq[hslice]
  __shared__ float alpha[16], beta[16];
  int tid = threadIdx.x;
  for (int idx = tid; idx < 1024; idx += 512){
    int d = idx >> 4, i = idx & 15;
    u[d][i] = W_in[(size_t)(h * 64 + d) * DMODEL + i];
  }
  if (tid < 64) cvec[tid] = b_in[h * 64 + tid];
  __syncthreads();
  if (tid < 16){
    float a = 0.f, be = 0.f;
    for (int d = 0; d < 64; ++d){
      float wk = W_in[(size_t)(512 + h * 64 + d) * DMODEL + tid];
      a  += u[d][tid] * wk;
      be += cvec[d] * wk;
    }
    alpha[tid] = a; beta[tid] = be;
  }
  __syncthreads();
  int t = tid;  // 0..511
  float K[64];
  const float* kp = Kf + (size_t)(t * BATCH + b) * DMODEL + h * 64;
  #pragma unroll
  for (int d = 0; d < 64; d += 4){
    float4 v = *reinterpret_cast<const float4*>(kp + d);
    K[d] = v.x; K[d+1] = v.y; K[d+2] = v.z; K[d+3] = v.w;
  }
  float Bt = 0.f;
  #pragma unroll
  for (int d = 0; d < 64; ++d) Bt += cvec[d] * K[d];
  for (int i = 0; i < 16; ++i){
    float A = 0.f;
    #pragma unroll
    for (int d = 0; d < 64; ++d) A += u[d][i] * K[d];
    float z = zcol[(size_t)(b * 16 + i) * 512 + t];
    G[(size_t)(bh * 16 + i) * 512 + t] = (A  - alpha[i] * z) * 0.125f;
    H[(size_t)(bh * 16 + i) * 512 + t] = (Bt - beta[i]  * z) * 0.125f;
  }
}

// ---------------- softmax accumulate v2: fold-reduce, transposed LDS ----------------
// grid: 32(bhl) * 32(sb) = 1024 blocks, 256 thr (4 waves); wave = 4 s-rows.
__global__ __launch_bounds__(256, 4) void k_sm2(const float* __restrict__ G,
    const float* __restrict__ H, const float* __restrict__ zcol, int bh0,
    float* __restrict__ R, unsigned short* __restrict__ Pb){
  int blk = blockIdx.x;
  int bhl = blk >> 5, sb = blk & 31;
  int bh = bh0 + bhl; int b = bh >> 3;
  __shared__ float Gt[8][68], Ht[8][68], Zt[8][68];
  int tid = threadIdx.x, l = tid & 63, w = tid >> 6;
  int s_w = sb * 16 + w * 4;

  float Pacc[4][8];
  #pragma unroll
  for (int r = 0; r < 4; ++r)
    #pragma unroll
    for (int j = 0; j < 8; ++j) Pacc[r][j] = 0.f;

  for (int i = 0; i < NI; ++i){
    // stage G/H/z transposed: elem t -> [t&7][t>>3]
    {
      const float* gp = G    + (((size_t)(bh * 16 + i)) << 9);
      const float* hp = H    + (((size_t)(bh * 16 + i)) << 9);
      const float* zp = zcol + (((size_t)(b  * 16 + i)) << 9);
      int t0 = tid, t1 = tid + 256;
      Gt[t0 & 7][t0 >> 3] = gp[t0];  Gt[t1 & 7][t1 >> 3] = gp[t1];
      Ht[t0 & 7][t0 >> 3] = hp[t0];  Ht[t1 & 7][t1 >> 3] = hp[t1];
      Zt[t0 & 7][t0 >> 3] = zp[t0];  Zt[t1 & 7][t1 >> 3] = zp[t1];
    }
    __syncthreads();

    float g[8], h[8], z[8];
    #pragma unroll
    for (int j = 0; j < 8; ++j){
      g[j] = Gt[j][l]; h[j] = Ht[j][l]; z[j] = Zt[j][l];
    }

    float e[4][8], pd[4], pr[4];
    #pragma unroll
    for (int r = 0; r < 4; ++r){
      int s = s_w + r;
      float y = Zt[s & 7][s >> 3];
      pd[r] = 0.f; pr[r] = 0.f;
      #pragma unroll
      for (int j = 0; j < 8; ++j){
        float ev = __expf(fmaf(y, g[j], h[j]));
        e[r][j] = ev;
        pd[r] += ev;
        pr[r] += ev * z[j];
      }
    }

    // fold-reduce 4 rows onto lane groups of 16, then 4-level butterfly
    bool b5 = (l & 32) != 0;
    bool b4 = (l & 16) != 0;
    // dsum chain
    float dk0 = b5 ? pd[2] : pd[0], ds0 = b5 ? pd[0] : pd[2];
    float dk1 = b5 ? pd[3] : pd[1], ds1 = b5 ? pd[1] : pd[3];
    // rsum chain (interleaved for ILP)
    float rk0 = b5 ? pr[2] : pr[0], rs0 = b5 ? pr[0] : pr[2];
    float rk1 = b5 ? pr[3] : pr[1], rs1 = b5 ? pr[1] : pr[3];
    float dq0 = dk0 + __shfl_xor(ds0, 32);
    float dq1 = dk1 + __shfl_xor(ds1, 32);
    float rq0 = rk0 + __shfl_xor(rs0, 32);
    float rq1 = rk1 + __shfl_xor(rs1, 32);
    float dkk = b4 ? dq1 : dq0, dss = b4 ? dq0 : dq1;
    float rkk = b4 ? rq1 : rq0, rss = b4 ? rq0 : rq1;
    float du = dkk + __shfl_xor(dss, 16);
    float ru = rkk + __shfl_xor(rss, 16);
    du += __shfl_xor(du, 8);  ru += __shfl_xor(ru, 8);
    du += __shfl_xor(du, 4);  ru += __shfl_xor(ru, 4);
    du += __shfl_xor(du, 2);  ru += __shfl_xor(ru, 2);
    du += __shfl_xor(du, 1);  ru += __shfl_xor(ru, 1);
    // lane group g holds row s_w+g totals
    float inv = __builtin_amdgcn_rcpf(du);
    if ((l & 15) == 0){
      int gr = l >> 4;
      R[((size_t)(bh * 512 + s_w + gr)) * 16 + i] = ru * inv;
    }
    float invr[4];
    #pragma unroll
    for (int r = 0; r < 4; ++r) invr[r] = __shfl(inv, r * 16);
    #pragma unroll
    for (int r = 0; r < 4; ++r)
      #pragma unroll
      for (int j = 0; j < 8; ++j) Pacc[r][j] += e[r][j] * invr[r];
    __syncthreads();
  }

  #pragma unroll
  for (int r = 0; r < 4; ++r){
    int s = s_w + r;
    unsigned int p0 = (unsigned int)f2bf(Pacc[r][0]) | ((unsigned int)f2bf(Pacc[r][1]) << 16);
    unsigned int p1 = (unsigned int)f2bf(Pacc[r][2]) | ((unsigned int)f2bf(Pacc[r][3]) << 16);
    unsigned int p2 = (unsigned int)f2bf(Pacc[r][4]) | ((unsigned int)f2bf(Pacc[r][5]) << 16);
    unsigned int p3 = (unsigned int)f2bf(Pacc[r][6]) | ((unsigned int)f2bf(Pacc[r][7]) << 16);
    uint4 pk; pk.x = p0; pk.y = p1; pk.z = p2; pk.w = p3;
    *reinterpret_cast<uint4*>(Pb + (size_t)(bhl * 512 + s) * 512 + l * 8) = pk;
  }
}

// ---------------- PV: O = Pbar @ Vf - R@Wv^T; 128x64 tile, LDS-staged ----------------
__global__ __launch_bounds__(256) void k_pv2(const unsigned short* __restrict__ Pb,
    const unsigned short* __restrict__ VfT, const float* __restrict__ R,
    const float* __restrict__ W_in, int bh0, unsigned short* __restrict__ Ob){
  __shared__ unsigned short As[2][128 * 32];
  __shared__ unsigned short Bs[2][64 * 32];
  __shared__ float Rl[128][17];
  __shared__ float Wvl[64][17];
  int bid = blockIdx.x;
  int bhl = bid >> 2, st = bid & 3;
  int bh = bh0 + bhl; int b = bh >> 3, h = bh & 7;
  int tid = threadIdx.x;
  int w = tid >> 6, l = tid & 63;
  int ln = l & 15, kb = l >> 4;
  int wr = w >> 1, wc = w & 1;

  const unsigned short* Abase = Pb + (size_t)(bhl * 512 + st * 128) * S_LEN;
  const unsigned short* Bbase = VfT + (size_t)b * (DMODEL * S_LEN) + (size_t)(h * 64) * S_LEN;

  for (int idx = tid; idx < 128 * 16; idx += 256){
    int sl = idx >> 4, i = idx & 15;
    Rl[sl][i] = R[(size_t)(bh * 512 + st * 128 + sl) * 16 + i];
  }
  for (int idx = tid; idx < 64 * 16; idx += 256){
    int dl = idx >> 4, i = idx & 15;
    Wvl[dl][i] = W_in[(size_t)(1024 + h * 64 + dl) * DMODEL + i];
  }

  f32x4 acc[4][2];
  #pragma unroll
  for (int mi = 0; mi < 4; ++mi)
    #pragma unroll
    for (int nj = 0; nj < 2; ++nj) acc[mi][nj] = (f32x4){0.f,0.f,0.f,0.f};

  int c0 = tid, c1 = 256 + tid;
  int r0 = c0 >> 2, q0 = c0 & 3, r1 = c1 >> 2, q1 = c1 & 3;
  int lb0 = (w * 64) * 8, lb1 = (256 + w * 64) * 8;

  #define STAGE_PV(kt, buf) do { int k0 = (kt) * 32;                              \
    async16(Abase + (size_t)r0 * S_LEN + k0 + q0 * 8, &As[buf][lb0]);             \
    async16(Abase + (size_t)r1 * S_LEN + k0 + q1 * 8, &As[buf][lb1]);             \
    async16(Bbase + (size_t)r0 * S_LEN + k0 + q0 * 8, &Bs[buf][lb0]);             \
  } while(0)

  STAGE_PV(0, 0);
  __syncthreads();
  int cur = 0;
  for (int kt = 0; kt < 16; ++kt){
    if (kt < 15) STAGE_PV(kt + 1, cur ^ 1);
    const unsigned short* Ab = &As[cur][(wr * 64 + ln) * 32 + kb * 8];
    const unsigned short* Bb = &Bs[cur][(wc * 32 + ln) * 32 + kb * 8];
    s16x8 af[4], bf[2];
    #pragma unroll
    for (int mi = 0; mi < 4; ++mi) af[mi] = *reinterpret_cast<const s16x8*>(Ab + mi * 16 * 32);
    #pragma unroll
    for (int nj = 0; nj < 2; ++nj) bf[nj] = *reinterpret_cast<const s16x8*>(Bb + nj * 16 * 32);
    #pragma unroll
    for (int mi = 0; mi < 4; ++mi)
      #pragma unroll
      for (int nj = 0; nj < 2; ++nj)
        acc[mi][nj] = __builtin_amdgcn_mfma_f32_16x16x32_bf16(af[mi], bf[nj], acc[mi][nj], 0, 0, 0);
    __syncthreads();
    cur ^= 1;
  }
  #undef STAGE_PV

  #pragma unroll
  for (int nj = 0; nj < 2; ++nj){
    int dl = wc * 32 + nj * 16 + ln;
    #pragma unroll
    for (int mi = 0; mi < 4; ++mi){
      #pragma unroll
      for (int r = 0; r < 4; ++r){
        int ml = wr * 64 + mi * 16 + kb * 4 + r;
        int m = st * 128 + ml;   // s index
        float corr = 0.f;
        #pragma unroll
        for (int i = 0; i < 16; ++i) corr += Rl[ml][i] * Wvl[dl][i];
        float v = acc[mi][nj][r] - corr;
        Ob[(size_t)(m * BATCH + b) * DMODEL + h * 64 + dl] = f2bf(v);
      }
    }
  }
}

// ---------------- out-proj: out = Ob @ W_out^T + 16*b_out, 128x128 tile ----------------
__global__ __launch_bounds__(256) void k_out2(const unsigned short* __restrict__ Ob,
    const unsigned short* __restrict__ Wob, const float* __restrict__ b_out,
    float* __restrict__ out){
  __shared__ unsigned short As[2][128 * 32];
  __shared__ unsigned short Bs[2][128 * 32];
  int tid = threadIdx.x;
  int w = tid >> 6, l = tid & 63;
  int ln = l & 15, kb = l >> 4;
  int wr = w >> 1, wc = w & 1;
  int m0 = blockIdx.x * 128;
  int n0 = blockIdx.y * 128;

  f32x4 acc[4][4];
  #pragma unroll
  for (int mi = 0; mi < 4; ++mi)
    #pragma unroll
    for (int nj = 0; nj < 4; ++nj) acc[mi][nj] = (f32x4){0.f,0.f,0.f,0.f};

  int c0 = tid, c1 = 256 + tid;
  int r0 = c0 >> 2, q0 = c0 & 3, r1 = c1 >> 2, q1 = c1 & 3;
  int lb0 = (w * 64) * 8, lb1 = (256 + w * 64) * 8;

  #define STAGE_O(kt, buf) do { int k0 = (kt) * 32;                                    \
    async16(Ob  + (size_t)(m0 + r0) * DMODEL + k0 + q0 * 8, &As[buf][lb0]);            \
    async16(Ob  + (size_t)(m0 + r1) * DMODEL + k0 + q1 * 8, &As[buf][lb1]);            \
    async16(Wob + (size_t)(n0 + r0) * DMODEL + k0 + q0 * 8, &Bs[buf][lb0]);            \
    async16(Wob + (size_t)(n0 + r1) * DMODEL + k0 + q1 * 8, &Bs[buf][lb1]);            \
  } while(0)

  STAGE_O(0, 0);
  __syncthreads();
  int cur = 0;
  for (int kt = 0; kt < 16; ++kt){
    if (kt < 15) STAGE_O(kt + 1, cur ^ 1);
    const unsigned short* Ab = &As[cur][(wr * 64 + ln) * 32 + kb * 8];
    const unsigned short* Bb = &Bs[cur][(wc * 64 + ln) * 32 + kb * 8];
    s16x8 af[4], bf[4];
    #pragma unroll
    for (int mi = 0; mi < 4; ++mi) af[mi] = *reinterpret_cast<const s16x8*>(Ab + mi * 16 * 32);
    #pragma unroll
    for (int nj = 0; nj < 4; ++nj) bf[nj] = *reinterpret_cast<const s16x8*>(Bb + nj * 16 * 32);
    #pragma unroll
    for (int mi = 0; mi < 4; ++mi)
      #pragma unroll
      for (int nj = 0; nj < 4; ++nj)
        acc[mi][nj] = __builtin_amdgcn_mfma_f32_16x16x32_bf16(af[mi], bf[nj], acc[mi][nj], 0, 0, 0);
    __syncthreads();
    cur ^= 1;
  }
  #undef STAGE_O

  #pragma unroll
  for (int nj = 0; nj < 4; ++nj){
    int n = n0 + wc * 64 + nj * 16 + ln;
    float bias = 16.0f * b_out[n];
    #pragma unroll
    for (int mi = 0; mi < 4; ++mi){
      #pragma unroll
      for (int r = 0; r < 4; ++r){
        int m = m0 + wr * 64 + mi * 16 + kb * 4 + r;
        out[(size_t)m * DMODEL + n] = acc[mi][nj][r] + bias;
      }
    }
  }
}

extern "C" void kernel_launch(void* const* d_in, const int* in_sizes, int n_in,
                              void* d_out, int out_size, void* d_ws, size_t ws_size,
                              hipStream_t stream) {
  const float* x     = (const float*)d_in[0];
  const float* W_in  = (const float*)d_in[1];
  const float* b_in  = (const float*)d_in[2];
  const float* W_out = (const float*)d_in[3];
  const float* b_out = (const float*)d_in[4];
  float* out = (float*)d_out;

  size_t off = 0;
  char* base = (char*)d_ws;
  auto alloc = [&](size_t bytes) -> void* {
    void* p = base + off;
    off += (bytes + 255) & ~(size_t)255;
    return p;
  };
  unsigned short* xb   = (unsigned short*)alloc(8388608);    // x bf16
  unsigned short* Winb = (unsigned short*)alloc(1572864);    // W_in bf16
  unsigned short* Wob  = (unsigned short*)alloc(524288);     // W_out bf16
  float*          zcol = (float*)alloc(524288);              // [b][i][t]
  float*          Kf   = (float*)alloc(16777216);            // [r][d] f32
  unsigned short* Vfb  = (unsigned short*)alloc(8388608);    // [r][d] bf16
  unsigned short* VfT  = (unsigned short*)alloc(8388608);    // [b][d][t] bf16
  float*          G    = (float*)alloc(4194304);             // [bh][i][t]
  float*          H    = (float*)alloc(4194304);             // [bh][i][t]
  float*          R    = (float*)alloc(4194304);             // [bh][s][i]
  unsigned short* Ob   = (unsigned short*)alloc(8388608);    // [r][d] bf16
  unsigned short* Pb   = (unsigned short*)alloc(16777216);   // chunk: [32 bh][s][t] bf16

  k_cvt<<<4096, 256, 0, stream>>>(x, xb);
  k_cvt<<<768, 256, 0, stream>>>(W_in, Winb);
  k_cvt<<<256, 256, 0, stream>>>(W_out, Wob);
  k_zcol<<<512, 256, 0, stream>>>(x, zcol);

  { dim3 g(64, 8); k_kv2<<<g, 256, 0, stream>>>(xb, Winb, b_in, Kf, Vfb); }
  { dim3 g(16, 16, 16); k_tr<<<g, 256, 0, stream>>>(Vfb, VfT); }
  k_gh<<<128, 512, 0, stream>>>(W_in, b_in, Kf, zcol, G, H);

  for (int c = 0; c < 4; ++c){
    k_sm2<<<1024, 256, 0, stream>>>(G, H, zcol, c * 32, R, Pb);
    k_pv2<<<128, 256, 0, stream>>>(Pb, VfT, R, W_in, c * 32, Ob);
  }

  { dim3 g(64, 4); k_out2<<<g, 256, 0, stream>>>(Ob, Wob, b_out, out); }
}

// Round 4
// 186.343 us; speedup vs baseline: 2.9655x; 1.5625x over previous
//
#include <hip/hip_runtime.h>

// Problem constants
#define S_LEN 512
#define BATCH 16
#define DMODEL 512
#define NHEAD 8
#define DH 64
#define NI 16      // loop count = x.shape[1] = 16 channel iterations

typedef float f32x4 __attribute__((ext_vector_type(4)));
typedef float f32x2 __attribute__((ext_vector_type(2)));
typedef short s16x8 __attribute__((ext_vector_type(8)));

__device__ __forceinline__ unsigned short f2bf(float f){
  unsigned int u = __float_as_uint(f);
  u += 0x7FFFu + ((u >> 16) & 1u);   // RNE
  return (unsigned short)(u >> 16);
}

// async global->LDS 16B copy; lds ptr wave-uniform (HW adds lane*16)
__device__ __forceinline__ void async16(const unsigned short* g, unsigned short* l){
  __builtin_amdgcn_global_load_lds(
      (const __attribute__((address_space(1))) unsigned int*)g,
      (__attribute__((address_space(3))) unsigned int*)l, 16, 0, 0);
}

// x + dpp_permuted(x): VALU-pipe butterfly level (within 16-lane DPP rows)
template<int CTRL>
__device__ __forceinline__ float dppAdd(float x){
  int v = __builtin_amdgcn_update_dpp(0, __float_as_int(x), CTRL, 0xF, 0xF, true);
  return x + __int_as_float(v);
}

// ---------------- prep: x -> xb (bf16), zcol[b][i][t] = x[t][b][i] ----------------
__global__ void k_prep(const float* __restrict__ x, unsigned short* __restrict__ xb,
                       float* __restrict__ zcol){
  int bidx = blockIdx.x;
  if (bidx < 4096){
    int t = bidx * 256 + threadIdx.x;
    float4 v = reinterpret_cast<const float4*>(x)[t];
    ushort4 o;
    o.x = f2bf(v.x); o.y = f2bf(v.y); o.z = f2bf(v.z); o.w = f2bf(v.w);
    reinterpret_cast<ushort4*>(xb)[t] = o;
  } else {
    int tid = (bidx - 4096) * 256 + threadIdx.x;     // 131072
    int t = tid & 511; int bi = tid >> 9; int b = bi >> 4; int i = bi & 15;
    zcol[tid] = x[(size_t)(t * BATCH + b) * DMODEL + i];
  }
}

// ---------------- weight cvt: W_in, W_out -> bf16 ----------------
__global__ void k_wcvt(const float* __restrict__ Win, const float* __restrict__ Wout,
                       unsigned short* __restrict__ Winb, unsigned short* __restrict__ Wob){
  int bidx = blockIdx.x;
  if (bidx < 768){
    int t = bidx * 256 + threadIdx.x;
    float4 v = reinterpret_cast<const float4*>(Win)[t];
    ushort4 o;
    o.x = f2bf(v.x); o.y = f2bf(v.y); o.z = f2bf(v.z); o.w = f2bf(v.w);
    reinterpret_cast<ushort4*>(Winb)[t] = o;
  } else {
    int t = (bidx - 768) * 256 + threadIdx.x;
    float4 v = reinterpret_cast<const float4*>(Wout)[t];
    ushort4 o;
    o.x = f2bf(v.x); o.y = f2bf(v.y); o.z = f2bf(v.z); o.w = f2bf(v.w);
    reinterpret_cast<ushort4*>(Wob)[t] = o;
  }
}

// ---------------- K/V projection, 128x128 tile, global_load_lds dbuf ----------------
__global__ __launch_bounds__(256) void k_kv2(const unsigned short* __restrict__ xb,
    const unsigned short* __restrict__ Winb, const float* __restrict__ b_in,
    float* __restrict__ Kf, unsigned short* __restrict__ Vfb){
  __shared__ unsigned short As[2][128 * 32];
  __shared__ unsigned short Bs[2][128 * 32];
  int tid = threadIdx.x;
  int w = tid >> 6, l = tid & 63;
  int ln = l & 15, kb = l >> 4;
  int wr = w >> 1, wc = w & 1;
  int m0 = blockIdx.x * 128;
  int n0 = blockIdx.y * 128;
  const unsigned short* Brow = Winb + (size_t)512 * DMODEL;

  f32x4 acc[4][4];
  #pragma unroll
  for (int mi = 0; mi < 4; ++mi)
    #pragma unroll
    for (int nj = 0; nj < 4; ++nj) acc[mi][nj] = (f32x4){0.f,0.f,0.f,0.f};

  int c0 = tid, c1 = 256 + tid;
  int r0 = c0 >> 2, q0 = c0 & 3, r1 = c1 >> 2, q1 = c1 & 3;
  int lb0 = (w * 64) * 8, lb1 = (256 + w * 64) * 8;

  #define STAGE_KV(kt, buf) do { int k0 = (kt) * 32;                                   \
    async16(xb   + (size_t)(m0 + r0) * DMODEL + k0 + q0 * 8, &As[buf][lb0]);           \
    async16(xb   + (size_t)(m0 + r1) * DMODEL + k0 + q1 * 8, &As[buf][lb1]);           \
    async16(Brow + (size_t)(n0 + r0) * DMODEL + k0 + q0 * 8, &Bs[buf][lb0]);           \
    async16(Brow + (size_t)(n0 + r1) * DMODEL + k0 + q1 * 8, &Bs[buf][lb1]);           \
  } while(0)

  STAGE_KV(0, 0);
  __syncthreads();
  int cur = 0;
  for (int kt = 0; kt < 16; ++kt){
    if (kt < 15) STAGE_KV(kt + 1, cur ^ 1);
    const unsigned short* Ab = &As[cur][(wr * 64 + ln) * 32 + kb * 8];
    const unsigned short* Bb = &Bs[cur][(wc * 64 + ln) * 32 + kb * 8];
    s16x8 af[4], bf[4];
    #pragma unroll
    for (int mi = 0; mi < 4; ++mi) af[mi] = *reinterpret_cast<const s16x8*>(Ab + mi * 16 * 32);
    #pragma unroll
    for (int nj = 0; nj < 4; ++nj) bf[nj] = *reinterpret_cast<const s16x8*>(Bb + nj * 16 * 32);
    #pragma unroll
    for (int mi = 0; mi < 4; ++mi)
      #pragma unroll
      for (int nj = 0; nj < 4; ++nj)
        acc[mi][nj] = __builtin_amdgcn_mfma_f32_16x16x32_bf16(af[mi], bf[nj], acc[mi][nj], 0, 0, 0);
    __syncthreads();
    cur ^= 1;
  }
  #undef STAGE_KV

  #pragma unroll
  for (int nj = 0; nj < 4; ++nj){
    int n = n0 + wc * 64 + nj * 16 + ln;
    float bias = b_in[512 + n];
    #pragma unroll
    for (int mi = 0; mi < 4; ++mi){
      #pragma unroll
      for (int r = 0; r < 4; ++r){
        int m = m0 + wr * 64 + mi * 16 + kb * 4 + r;
        float v = acc[mi][nj][r] + bias;
        if (n < DMODEL) Kf[(size_t)m * DMODEL + n] = v;
        else            Vfb[(size_t)m * DMODEL + (n - DMODEL)] = f2bf(v);
      }
    }
  }
}

// ---------------- transpose Vfb [t*B+b][d] -> VfT [b][d][t] (bf16) ----------------
__global__ void k_tr(const unsigned short* __restrict__ Vfb, unsigned short* __restrict__ VfT){
  __shared__ unsigned short tile[32][34];
  int b = blockIdx.z; int t0 = blockIdx.x * 32; int d0 = blockIdx.y * 32;
  int tx = threadIdx.x & 31, ty = threadIdx.x >> 5;   // 32 x 8
  #pragma unroll
  for (int k = 0; k < 4; ++k){
    int row = ty + 8 * k;
    tile[row][tx] = Vfb[(size_t)((t0 + row) * BATCH + b) * DMODEL + d0 + tx];
  }
  __syncthreads();
  #pragma unroll
  for (int k = 0; k < 4; ++k){
    int row = ty + 8 * k;
    VfT[(size_t)b * (DMODEL * S_LEN) + (size_t)(d0 + row) * S_LEN + t0 + tx] = tile[tx][row];
  }
}

// ---------------- G,H precompute (scaled by 1/8 * log2(e) for exp2 path) ----------------
__global__ __launch_bounds__(512) void k_gh(const float* __restrict__ W_in,
    const float* __restrict__ b_in, const float* __restrict__ Kf,
    const float* __restrict__ zcol, float* __restrict__ G, float* __restrict__ H){
  const float SCALE = 0.18033688011112042f;   // 0.125 * log2(e)
  int bh = blockIdx.x; int b = bh >> 3, h = bh & 7;
  __shared__ float u[64][17];     // u[d][i] = Wq[h*64+d][i]
  __shared__ float cvec[64];      // bq[hslice]
  __shared__ float alpha[16], beta[16];
  int tid = threadIdx.x;
  for (int idx = tid; idx < 1024; idx += 512){
    int d = idx >> 4, i = idx & 15;
    u[d][i] = W_in[(size_t)(h * 64 + d) * DMODEL + i];
  }
  if (tid < 64) cvec[tid] = b_in[h * 64 + tid];
  __syncthreads();
  if (tid < 16){
    float a = 0.f, be = 0.f;
    for (int d = 0; d < 64; ++d){
      float wk = W_in[(size_t)(512 + h * 64 + d) * DMODEL + tid];
      a  += u[d][tid] * wk;
      be += cvec[d] * wk;
    }
    alpha[tid] = a; beta[tid] = be;
  }
  __syncthreads();
  int t = tid;  // 0..511
  float K[64];
  const float* kp = Kf + (size_t)(t * BATCH + b) * DMODEL + h * 64;
  #pragma unroll
  for (int d = 0; d < 64; d += 4){
    float4 v = *reinterpret_cast<const float4*>(kp + d);
    K[d] = v.x; K[d+1] = v.y; K[d+2] = v.z; K[d+3] = v.w;
  }
  float Bt = 0.f;
  #pragma unroll
  for (int d = 0; d < 64; ++d) Bt += cvec[d] * K[d];
  for (int i = 0; i < 16; ++i){
    float A = 0.f;
    #pragma unroll
    for (int d = 0; d < 64; ++d) A += u[d][i] * K[d];
    float z = zcol[(size_t)(b * 16 + i) * 512 + t];
    G[(size_t)(bh * 16 + i) * 512 + t] = (A  - alpha[i] * z) * SCALE;
    H[(size_t)(bh * 16 + i) * 512 + t] = (Bt - beta[i]  * z) * SCALE;
  }
}

// ---------------- fused softmax + PV: one block = (bh, 16 s-rows) ----------------
// phase 1: accumulate Pbar rows (strided t-ownership, DPP reduce, exp2), R -> LDS
// phase 2: O = Pbar @ Vf - R @ Wv^T via MFMA (Pbar in swizzled LDS)
__global__ __launch_bounds__(256) void k_smpv(const float* __restrict__ G,
    const float* __restrict__ H, const float* __restrict__ zcol,
    const unsigned short* __restrict__ VfT, const float* __restrict__ W_in,
    unsigned short* __restrict__ Ob){
  __shared__ unsigned short Pl[16 * 512];   // [s][t] bf16, byte-XOR-swizzled (bits 4-6)
  __shared__ float Rs[16][17];
  __shared__ float Wvl[64][17];
  int bid = blockIdx.x;
  int bh = bid >> 5, sb = bid & 31;
  int b = bh >> 3, h = bh & 7;
  int tid = threadIdx.x, w = tid >> 6, l = tid & 63;

  { // Wv slice for correction: [64 d][16 i]
    int d = tid >> 2, i0 = (tid & 3) * 4;
    const float* wp = W_in + (size_t)(2 * DMODEL + h * 64 + d) * DMODEL + i0;
    float4 v = *reinterpret_cast<const float4*>(wp);
    Wvl[d][i0] = v.x; Wvl[d][i0+1] = v.y; Wvl[d][i0+2] = v.z; Wvl[d][i0+3] = v.w;
  }

  const float* gb = G    + ((size_t)bh * NI) * S_LEN;
  const float* hb = H    + ((size_t)bh * NI) * S_LEN;
  const float* zb = zcol + ((size_t)b  * NI) * S_LEN;
  int t0 = l * 4, t1 = 256 + l * 4;   // this lane's t ownership (2 x 4 contiguous)
  int sg0 = sb * 16 + w * 4;          // this wave's 4 s-rows (global s)

  f32x2 Pacc[4][4];
  #pragma unroll
  for (int r = 0; r < 4; ++r)
    #pragma unroll
    for (int jp = 0; jp < 4; ++jp) Pacc[r][jp] = (f32x2){0.f, 0.f};

  for (int i = 0; i < NI; ++i){
    const float* gp = gb + (i << 9);
    const float* hp = hb + (i << 9);
    const float* zp = zb + (i << 9);
    f32x4 gA = *reinterpret_cast<const f32x4*>(gp + t0);
    f32x4 gB = *reinterpret_cast<const f32x4*>(gp + t1);
    f32x4 hA = *reinterpret_cast<const f32x4*>(hp + t0);
    f32x4 hB = *reinterpret_cast<const f32x4*>(hp + t1);
    f32x4 zA = *reinterpret_cast<const f32x4*>(zp + t0);
    f32x4 zB = *reinterpret_cast<const f32x4*>(zp + t1);
    float4 y4 = *reinterpret_cast<const float4*>(zp + sg0);
    f32x2 g2[4] = {gA.lo, gA.hi, gB.lo, gB.hi};
    f32x2 h2[4] = {hA.lo, hA.hi, hB.lo, hB.hi};
    f32x2 z2[4] = {zA.lo, zA.hi, zB.lo, zB.hi};
    float ys[4] = {y4.x, y4.y, y4.z, y4.w};

    f32x2 E[4][4];
    float pd[4], pr[4];
    #pragma unroll
    for (int r = 0; r < 4; ++r){
      f32x2 yv = {ys[r], ys[r]};
      f32x2 dacc = {0.f, 0.f}, racc = {0.f, 0.f};
      #pragma unroll
      for (int jp = 0; jp < 4; ++jp){
        f32x2 a = yv * g2[jp] + h2[jp];
        f32x2 e;
        e.x = __builtin_amdgcn_exp2f(a.x);
        e.y = __builtin_amdgcn_exp2f(a.y);
        E[r][jp] = e;
        dacc += e;
        racc += e * z2[jp];
      }
      pd[r] = dacc.x + dacc.y;
      pr[r] = racc.x + racc.y;
    }

    // reduce: fold 4 rows onto 16-lane groups (2 ds-shuffle levels), then DPP butterfly
    bool b5 = (l & 32) != 0, b4 = (l & 16) != 0;
    float dk0 = b5 ? pd[2] : pd[0], dv0 = b5 ? pd[0] : pd[2];
    float dk1 = b5 ? pd[3] : pd[1], dv1 = b5 ? pd[1] : pd[3];
    float rk0 = b5 ? pr[2] : pr[0], rv0 = b5 ? pr[0] : pr[2];
    float rk1 = b5 ? pr[3] : pr[1], rv1 = b5 ? pr[1] : pr[3];
    float dq0 = dk0 + __shfl_xor(dv0, 32);
    float dq1 = dk1 + __shfl_xor(dv1, 32);
    float rq0 = rk0 + __shfl_xor(rv0, 32);
    float rq1 = rk1 + __shfl_xor(rv1, 32);
    float dkk = b4 ? dq1 : dq0, dss = b4 ? dq0 : dq1;
    float rkk = b4 ? rq1 : rq0, rss = b4 ? rq0 : rq1;
    float du = dkk + __shfl_xor(dss, 16);
    float ru = rkk + __shfl_xor(rss, 16);
    du = dppAdd<0x140>(du); ru = dppAdd<0x140>(ru);   // row_mirror
    du = dppAdd<0x141>(du); ru = dppAdd<0x141>(ru);   // row_half_mirror
    du = dppAdd<0x4E>(du);  ru = dppAdd<0x4E>(ru);    // quad_perm xor2
    du = dppAdd<0xB1>(du);  ru = dppAdd<0xB1>(ru);    // quad_perm xor1
    float inv = __builtin_amdgcn_rcpf(du);
    if ((l & 15) == 0)
      Rs[w * 4 + (l >> 4)][i] = ru * inv;
    #pragma unroll
    for (int r = 0; r < 4; ++r){
      float ir = __int_as_float(__builtin_amdgcn_readlane(__float_as_int(inv), 16 * r));
      f32x2 iv = {ir, ir};
      #pragma unroll
      for (int jp = 0; jp < 4; ++jp) Pacc[r][jp] += E[r][jp] * iv;
    }
  }

  // write Pbar to swizzled LDS (bf16)
  #pragma unroll
  for (int r = 0; r < 4; ++r){
    int sl = w * 4 + r;
    unsigned int u0 = (unsigned int)f2bf(Pacc[r][0].x) | ((unsigned int)f2bf(Pacc[r][0].y) << 16);
    unsigned int u1 = (unsigned int)f2bf(Pacc[r][1].x) | ((unsigned int)f2bf(Pacc[r][1].y) << 16);
    unsigned int u2 = (unsigned int)f2bf(Pacc[r][2].x) | ((unsigned int)f2bf(Pacc[r][2].y) << 16);
    unsigned int u3 = (unsigned int)f2bf(Pacc[r][3].x) | ((unsigned int)f2bf(Pacc[r][3].y) << 16);
    int xr = (sl & 7) << 4;
    char* rowp = (char*)Pl + sl * 1024;
    uint2 v01; v01.x = u0; v01.y = u1;
    uint2 v23; v23.x = u2; v23.y = u3;
    *reinterpret_cast<uint2*>(rowp + ((l * 8) ^ xr)) = v01;
    *reinterpret_cast<uint2*>(rowp + ((512 + l * 8) ^ xr)) = v23;
  }
  __syncthreads();

  // phase 2: per wave, 16x16 d-tile over K=512
  int ln = l & 15, kb = l >> 4;
  int dt = w * 16;
  const unsigned short* bp = VfT + (size_t)b * (DMODEL * S_LEN)
                             + (size_t)(h * 64 + dt + ln) * S_LEN + kb * 8;
  char* arow = (char*)Pl + ln * 1024;
  int xa = (ln & 7) << 4;
  f32x4 acc = {0.f, 0.f, 0.f, 0.f};
  #pragma unroll
  for (int kt = 0; kt < 16; ++kt){
    s16x8 af = *reinterpret_cast<const s16x8*>(arow + ((kt * 64 + kb * 16) ^ xa));
    s16x8 bf = *reinterpret_cast<const s16x8*>(bp + kt * 32);
    acc = __builtin_amdgcn_mfma_f32_16x16x32_bf16(af, bf, acc, 0, 0, 0);
  }
  #pragma unroll
  for (int r = 0; r < 4; ++r){
    int so = kb * 4 + r;
    float corr = 0.f;
    #pragma unroll
    for (int i = 0; i < 16; ++i) corr += Rs[so][i] * Wvl[dt + ln][i];
    float v = acc[r] - corr;
    int m = sb * 16 + so;
    Ob[(size_t)(m * BATCH + b) * DMODEL + h * 64 + dt + ln] = f2bf(v);
  }
}

// ---------------- out-proj: out = Ob @ W_out^T + 16*b_out, 128x128 tile ----------------
__global__ __launch_bounds__(256) void k_out2(const unsigned short* __restrict__ Ob,
    const unsigned short* __restrict__ Wob, const float* __restrict__ b_out,
    float* __restrict__ out){
  __shared__ unsigned short As[2][128 * 32];
  __shared__ unsigned short Bs[2][128 * 32];
  int tid = threadIdx.x;
  int w = tid >> 6, l = tid & 63;
  int ln = l & 15, kb = l >> 4;
  int wr = w >> 1, wc = w & 1;
  int m0 = blockIdx.x * 128;
  int n0 = blockIdx.y * 128;

  f32x4 acc[4][4];
  #pragma unroll
  for (int mi = 0; mi < 4; ++mi)
    #pragma unroll
    for (int nj = 0; nj < 4; ++nj) acc[mi][nj] = (f32x4){0.f,0.f,0.f,0.f};

  int c0 = tid, c1 = 256 + tid;
  int r0 = c0 >> 2, q0 = c0 & 3, r1 = c1 >> 2, q1 = c1 & 3;
  int lb0 = (w * 64) * 8, lb1 = (256 + w * 64) * 8;

  #define STAGE_O(kt, buf) do { int k0 = (kt) * 32;                                    \
    async16(Ob  + (size_t)(m0 + r0) * DMODEL + k0 + q0 * 8, &As[buf][lb0]);            \
    async16(Ob  + (size_t)(m0 + r1) * DMODEL + k0 + q1 * 8, &As[buf][lb1]);            \
    async16(Wob + (size_t)(n0 + r0) * DMODEL + k0 + q0 * 8, &Bs[buf][lb0]);            \
    async16(Wob + (size_t)(n0 + r1) * DMODEL + k0 + q1 * 8, &Bs[buf][lb1]);            \
  } while(0)

  STAGE_O(0, 0);
  __syncthreads();
  int cur = 0;
  for (int kt = 0; kt < 16; ++kt){
    if (kt < 15) STAGE_O(kt + 1, cur ^ 1);
    const unsigned short* Ab = &As[cur][(wr * 64 + ln) * 32 + kb * 8];
    const unsigned short* Bb = &Bs[cur][(wc * 64 + ln) * 32 + kb * 8];
    s16x8 af[4], bf[4];
    #pragma unroll
    for (int mi = 0; mi < 4; ++mi) af[mi] = *reinterpret_cast<const s16x8*>(Ab + mi * 16 * 32);
    #pragma unroll
    for (int nj = 0; nj < 4; ++nj) bf[nj] = *reinterpret_cast<const s16x8*>(Bb + nj * 16 * 32);
    #pragma unroll
    for (int mi = 0; mi < 4; ++mi)
      #pragma unroll
      for (int nj = 0; nj < 4; ++nj)
        acc[mi][nj] = __builtin_amdgcn_mfma_f32_16x16x32_bf16(af[mi], bf[nj], acc[mi][nj], 0, 0, 0);
    __syncthreads();
    cur ^= 1;
  }
  #undef STAGE_O

  #pragma unroll
  for (int nj = 0; nj < 4; ++nj){
    int n = n0 + wc * 64 + nj * 16 + ln;
    float bias = 16.0f * b_out[n];
    #pragma unroll
    for (int mi = 0; mi < 4; ++mi){
      #pragma unroll
      for (int r = 0; r < 4; ++r){
        int m = m0 + wr * 64 + mi * 16 + kb * 4 + r;
        out[(size_t)m * DMODEL + n] = acc[mi][nj][r] + bias;
      }
    }
  }
}

extern "C" void kernel_launch(void* const* d_in, const int* in_sizes, int n_in,
                              void* d_out, int out_size, void* d_ws, size_t ws_size,
                              hipStream_t stream) {
  const float* x     = (const float*)d_in[0];
  const float* W_in  = (const float*)d_in[1];
  const float* b_in  = (const float*)d_in[2];
  const float* W_out = (const float*)d_in[3];
  const float* b_out = (const float*)d_in[4];
  float* out = (float*)d_out;

  size_t off = 0;
  char* base = (char*)d_ws;
  auto alloc = [&](size_t bytes) -> void* {
    void* p = base + off;
    off += (bytes + 255) & ~(size_t)255;
    return p;
  };
  unsigned short* xb   = (unsigned short*)alloc(8388608);    // x bf16
  unsigned short* Winb = (unsigned short*)alloc(1572864);    // W_in bf16
  unsigned short* Wob  = (unsigned short*)alloc(524288);     // W_out bf16
  float*          zcol = (float*)alloc(524288);              // [b][i][t]
  float*          Kf   = (float*)alloc(16777216);            // [r][d] f32
  unsigned short* Vfb  = (unsigned short*)alloc(8388608);    // [r][d] bf16
  unsigned short* VfT  = (unsigned short*)alloc(8388608);    // [b][d][t] bf16
  float*          G    = (float*)alloc(4194304);             // [bh][i][t] (x log2e/8)
  float*          H    = (float*)alloc(4194304);             // [bh][i][t] (x log2e/8)
  unsigned short* Ob   = (unsigned short*)alloc(8388608);    // [r][d] bf16

  k_prep<<<4608, 256, 0, stream>>>(x, xb, zcol);
  k_wcvt<<<1024, 256, 0, stream>>>(W_in, W_out, Winb, Wob);

  { dim3 g(64, 8); k_kv2<<<g, 256, 0, stream>>>(xb, Winb, b_in, Kf, Vfb); }
  { dim3 g(16, 16, 16); k_tr<<<g, 256, 0, stream>>>(Vfb, VfT); }
  k_gh<<<128, 512, 0, stream>>>(W_in, b_in, Kf, zcol, G, H);

  k_smpv<<<4096, 256, 0, stream>>>(G, H, zcol, VfT, W_in, Ob);

  { dim3 g(64, 4); k_out2<<<g, 256, 0, stream>>>(Ob, Wob, b_out, out); }
}